// Round 6
// baseline (490.406 us; speedup 1.0000x reference)
//
#include <hip/hip_runtime.h>

#define SEQL 2048
#define DMODEL 1024
#define HDIM 8192  // H*D

typedef unsigned short bf16_t;
typedef __attribute__((ext_vector_type(8))) short bf16x8;
typedef __attribute__((ext_vector_type(4))) float f32x4;

__device__ __forceinline__ bf16_t f2bf(float f) {
  unsigned u = __float_as_uint(f);
  u += 0x7fffu + ((u >> 16) & 1u);  // RNE
  return (bf16_t)(u >> 16);
}
__device__ __forceinline__ float bf2f(bf16_t b) {
  return __uint_as_float(((unsigned)b) << 16);
}
__device__ __forceinline__ void st(bf16_t* p, float v) { *p = f2bf(v); }
__device__ __forceinline__ void st(float* p, float v) { *p = v; }

// ---------------- elementwise f32 -> bf16 ----------------
__global__ __launch_bounds__(256) void cvt_f32_bf16(const float* __restrict__ in,
                                                    bf16_t* __restrict__ out, int n) {
  int i = (blockIdx.x * 256 + threadIdx.x) * 4;
  if (i >= n) return;
  float4 f = *reinterpret_cast<const float4*>(in + i);
  ushort4 u;
  u.x = f2bf(f.x); u.y = f2bf(f.y); u.z = f2bf(f.z); u.w = f2bf(f.w);
  *reinterpret_cast<ushort4*>(out + i) = u;
}

// tokens (DMODEL x SEQL) f32 -> tokensT (SEQL x DMODEL) bf16
__global__ __launch_bounds__(256) void transpose_cvt(const float* __restrict__ in,
                                                     bf16_t* __restrict__ out) {
  __shared__ float tile[32][33];
  int bx = blockIdx.x * 32;  // seq j
  int by = blockIdx.y * 32;  // channel c
  int tx = threadIdx.x, ty = threadIdx.y;
#pragma unroll
  for (int i = ty; i < 32; i += 8)
    tile[i][tx] = in[(size_t)(by + i) * SEQL + bx + tx];
  __syncthreads();
#pragma unroll
  for (int i = ty; i < 32; i += 8)
    out[(size_t)(bx + i) * DMODEL + by + tx] = f2bf(tile[tx][i]);
}

// Vsplit[h][d][m] = Vm[4m+h2, r*1024+d]  (h = 2*h2 + r), bf16 -> bf16
__global__ __launch_bounds__(256) void vsplit_k(const bf16_t* __restrict__ Vm,
                                                bf16_t* __restrict__ Vs) {
  __shared__ bf16_t tile[32][33];
  int h = blockIdx.z, h2 = h >> 1, r = h & 1;
  int m0 = blockIdx.x * 32, d0 = blockIdx.y * 32;
  int tx = threadIdx.x, ty = threadIdx.y;
#pragma unroll
  for (int i = ty; i < 32; i += 8)  // i: m offset, tx: d offset
    tile[i][tx] = Vm[(size_t)(4 * (m0 + i) + h2) * SEQL + r * DMODEL + d0 + tx];
  __syncthreads();
#pragma unroll
  for (int i = ty; i < 32; i += 8)  // i: d offset, tx: m offset
    Vs[((size_t)h * DMODEL + d0 + i) * SEQL + m0 + tx] = tile[tx][i];
}

// softmax over the 8 heads (dim 0), in place on bf16 S[8][L*L]
__global__ __launch_bounds__(256) void softmax_heads(bf16_t* __restrict__ S) {
  const size_t HS = (size_t)SEQL * SEQL;
  size_t p = ((size_t)blockIdx.x * 256 + threadIdx.x) * 8;
  float v[8][8];
#pragma unroll
  for (int h = 0; h < 8; ++h) {
    bf16x8 x = *reinterpret_cast<const bf16x8*>(S + h * HS + p);
#pragma unroll
    for (int e = 0; e < 8; ++e) v[h][e] = bf2f((bf16_t)x[e]);
  }
#pragma unroll
  for (int e = 0; e < 8; ++e) {
    float mx = v[0][e];
#pragma unroll
    for (int h = 1; h < 8; ++h) mx = fmaxf(mx, v[h][e]);
    float s = 0.f;
#pragma unroll
    for (int h = 0; h < 8; ++h) { v[h][e] = __expf(v[h][e] - mx); s += v[h][e]; }
    float inv = 1.0f / s;
#pragma unroll
    for (int h = 0; h < 8; ++h) v[h][e] *= inv;
  }
#pragma unroll
  for (int h = 0; h < 8; ++h) {
    bf16x8 x;
#pragma unroll
    for (int e = 0; e < 8; ++e) x[e] = (short)f2bf(v[h][e]);
    *reinterpret_cast<bf16x8*>(S + h * HS + p) = x;
  }
}

// reduce 8 f32 split-K partials P[z][D][L] -> out[D][L] + bias[row]
__global__ __launch_bounds__(256) void reduce_out(const float* __restrict__ P,
                                                  const float* __restrict__ bo,
                                                  float* __restrict__ out) {
  const size_t NEL = (size_t)DMODEL * SEQL;
  size_t i = ((size_t)blockIdx.x * 256 + threadIdx.x) * 4;
  float4 a = *reinterpret_cast<const float4*>(P + i);
#pragma unroll
  for (int z = 1; z < 8; ++z) {
    float4 b = *reinterpret_cast<const float4*>(P + z * NEL + i);
    a.x += b.x; a.y += b.y; a.z += b.z; a.w += b.w;
  }
  float bias = bo[i / SEQL];
  a.x += bias; a.y += bias; a.z += bias; a.w += bias;
  *reinterpret_cast<float4*>(out + i) = a;
}

// ---------------- C = scale * A·B^T (+bias[row]), 256x256 tile ----------------
// A: M x K (row stride lda), B: N x K (row stride ldb), bf16 K-contiguous.
// 512 threads = 8 waves (2M x 4N); per-wave output 128x64 = 8x4 frags of
// 16x16; BK=64; 64 MFMA / wave / K-tile.
// PER-PHASE schedule (m201 template, 4 phases per K-tile):
//   phase g: [stage half-tile(s) of t+1] -> ds_read quadrant regs ->
//            s_barrier -> lgkmcnt(0)+sched_barrier (rule 18) ->
//            setprio(1) 16 MFMA setprio(0) -> s_barrier
// Tile boundary: vmcnt(0)+s_barrier. All of t+1's stages were issued in
// phases 0-1 (>=2.5 phases old by then -> near-free); the per-wave
// vmcnt + barrier pair makes OTHER waves' staging visible before any
// ds_read of the next tile (vmcnt alone is per-wave!). WAR: each phase's
// lgkmcnt(0) retires its buffer reads before the trailing barrier that
// precedes any overwrite of that buffer. All waits are asm w/ memory
// clobber -> no load migrates across a phase.
// 8-slot XOR swizzle both sides (rule #21): LDS (row r, slot s) holds
// global k-chunk s ^ (r&7); global_load_lds dest linear, source
// pre-swizzled -> conflict-free ds_read_b128 (measured 0).
// Grid 1D per z-slice, XCD-chunked swizzle (T1), nwg % 8 == 0.
template <typename OutT, bool HAS_BIAS>
__global__ __launch_bounds__(512, 2) void gemm256(
    const bf16_t* __restrict__ A, const bf16_t* __restrict__ B,
    OutT* __restrict__ C, const float* __restrict__ bias,
    int M, int N, int K, int lda, int ldb, int ldc,
    long long sA, long long sB, long long sC, float scale, int gx) {
  __shared__ alignas(16) bf16_t As[2][2][128 * 64];
  __shared__ alignas(16) bf16_t Bs[2][2][128 * 64];
  const int z = blockIdx.z;
  A += (long long)z * sA;
  B += (long long)z * sB;
  C += (long long)z * sC;
  const int nwg = gridDim.x;
  const int bid = blockIdx.x;
  const int swz = (nwg & 7) ? bid : ((bid & 7) * (nwg >> 3) + (bid >> 3));
  const int brow = (swz / gx) * 256;
  const int bcol = (swz % gx) * 256;
  const int tid = threadIdx.x;
  const int w = tid >> 6, lane = tid & 63;
  const int fr = lane & 15, fq = lane >> 4;
  const int wr = w >> 2, wc = w & 3;

  // staging map: half-tile = 128x64 bf16 = 16KB = 2 loads/thread.
  int rj[2], cj[2];
#pragma unroll
  for (int j = 0; j < 2; ++j) {
    const int c = (w * 2 + j) * 64 + lane;
    rj[j] = c >> 3;
    cj[j] = ((c & 7) ^ (rj[j] & 7)) << 3;
  }

  auto stageA = [&](int buf, int half, int kk) {
#pragma unroll
    for (int j = 0; j < 2; ++j) {
      const bf16_t* g = A + (size_t)(brow + half * 128 + rj[j]) * lda + kk + cj[j];
      __builtin_amdgcn_global_load_lds(
          (const __attribute__((address_space(1))) void*)g,
          (__attribute__((address_space(3))) void*)(&As[buf][half][(w * 2 + j) * 512]),
          16, 0, 0);
    }
  };
  auto stageB = [&](int buf, int half, int kk) {
#pragma unroll
    for (int j = 0; j < 2; ++j) {
      const bf16_t* g = B + (size_t)(bcol + half * 128 + rj[j]) * ldb + kk + cj[j];
      __builtin_amdgcn_global_load_lds(
          (const __attribute__((address_space(1))) void*)g,
          (__attribute__((address_space(3))) void*)(&Bs[buf][half][(w * 2 + j) * 512]),
          16, 0, 0);
    }
  };

  // fragment reads (swizzled): logical k-chunk = kk*4+fq at row rr.
  auto ldA = [&](int buf, int mf, int kk) -> bf16x8 {
    const int rr = mf * 16 + fr;
    return *reinterpret_cast<const bf16x8*>(
        &As[buf][wr][rr * 64 + ((((kk << 2) | fq) ^ (rr & 7)) << 3)]);
  };
  auto ldB = [&](int buf, int nf, int kk) -> bf16x8 {
    const int rr = (wc & 1) * 64 + nf * 16 + fr;
    return *reinterpret_cast<const bf16x8*>(
        &Bs[buf][wc >> 1][rr * 64 + ((((kk << 2) | fq) ^ (rr & 7)) << 3)]);
  };

  f32x4 acc[8][4];
  const f32x4 fzero = {0.f, 0.f, 0.f, 0.f};
#pragma unroll
  for (int m = 0; m < 8; ++m)
#pragma unroll
    for (int n = 0; n < 4; ++n) acc[m][n] = fzero;

  const int NT = K >> 6;  // K % 64 == 0, NT >= 2 at all call sites

  // prologue: stage tile 0 (8 loads), drain, barrier
  stageA(0, 0, 0); stageA(0, 1, 0); stageB(0, 0, 0); stageB(0, 1, 0);
  asm volatile("s_waitcnt vmcnt(0)" ::: "memory");
  __builtin_amdgcn_sched_barrier(0);
  __builtin_amdgcn_s_barrier();

  for (int t = 0; t < NT; ++t) {
    const int p = t & 1, q = p ^ 1;
    const int kn = (t + 1) << 6;
    const bool pre = (t + 1 < NT);
    bf16x8 af[4][2], bg[4][2];

    // ---- phase 0: acc[0-3][0-1] ----
    if (pre) { stageA(q, 0, kn); stageA(q, 1, kn); }
#pragma unroll
    for (int mf = 0; mf < 4; ++mf)
#pragma unroll
      for (int kk = 0; kk < 2; ++kk) af[mf][kk] = ldA(p, mf, kk);
#pragma unroll
    for (int nf = 0; nf < 2; ++nf)
#pragma unroll
      for (int kk = 0; kk < 2; ++kk) bg[nf][kk] = ldB(p, nf, kk);
    __builtin_amdgcn_s_barrier();
    asm volatile("s_waitcnt lgkmcnt(0)" ::: "memory");
    __builtin_amdgcn_sched_barrier(0);
    __builtin_amdgcn_s_setprio(1);
#pragma unroll
    for (int mf = 0; mf < 4; ++mf)
#pragma unroll
      for (int nf = 0; nf < 2; ++nf)
#pragma unroll
        for (int kk = 0; kk < 2; ++kk)
          acc[mf][nf] = __builtin_amdgcn_mfma_f32_16x16x32_bf16(
              af[mf][kk], bg[nf][kk], acc[mf][nf], 0, 0, 0);
    __builtin_amdgcn_s_setprio(0);
    __builtin_amdgcn_s_barrier();

    // ---- phase 1: acc[0-3][2-3] ----
    if (pre) { stageB(q, 0, kn); stageB(q, 1, kn); }
#pragma unroll
    for (int nf = 2; nf < 4; ++nf)
#pragma unroll
      for (int kk = 0; kk < 2; ++kk) bg[nf][kk] = ldB(p, nf, kk);
    __builtin_amdgcn_s_barrier();
    asm volatile("s_waitcnt lgkmcnt(0)" ::: "memory");
    __builtin_amdgcn_sched_barrier(0);
    __builtin_amdgcn_s_setprio(1);
#pragma unroll
    for (int mf = 0; mf < 4; ++mf)
#pragma unroll
      for (int nf = 2; nf < 4; ++nf)
#pragma unroll
        for (int kk = 0; kk < 2; ++kk)
          acc[mf][nf] = __builtin_amdgcn_mfma_f32_16x16x32_bf16(
              af[mf][kk], bg[nf][kk], acc[mf][nf], 0, 0, 0);
    __builtin_amdgcn_s_setprio(0);
    __builtin_amdgcn_s_barrier();

    // ---- phase 2: acc[4-7][2-3] ----
#pragma unroll
    for (int mf = 0; mf < 4; ++mf)
#pragma unroll
      for (int kk = 0; kk < 2; ++kk) af[mf][kk] = ldA(p, mf + 4, kk);
    __builtin_amdgcn_s_barrier();
    asm volatile("s_waitcnt lgkmcnt(0)" ::: "memory");
    __builtin_amdgcn_sched_barrier(0);
    __builtin_amdgcn_s_setprio(1);
#pragma unroll
    for (int mf = 0; mf < 4; ++mf)
#pragma unroll
      for (int nf = 2; nf < 4; ++nf)
#pragma unroll
        for (int kk = 0; kk < 2; ++kk)
          acc[mf + 4][nf] = __builtin_amdgcn_mfma_f32_16x16x32_bf16(
              af[mf][kk], bg[nf][kk], acc[mf + 4][nf], 0, 0, 0);
    __builtin_amdgcn_s_setprio(0);
    __builtin_amdgcn_s_barrier();

    // ---- phase 3: acc[4-7][0-1] ----
#pragma unroll
    for (int nf = 0; nf < 2; ++nf)
#pragma unroll
      for (int kk = 0; kk < 2; ++kk) bg[nf][kk] = ldB(p, nf, kk);
    __builtin_amdgcn_s_barrier();
    asm volatile("s_waitcnt lgkmcnt(0)" ::: "memory");
    __builtin_amdgcn_sched_barrier(0);
    __builtin_amdgcn_s_setprio(1);
#pragma unroll
    for (int mf = 0; mf < 4; ++mf)
#pragma unroll
      for (int nf = 0; nf < 2; ++nf)
#pragma unroll
        for (int kk = 0; kk < 2; ++kk)
          acc[mf + 4][nf] = __builtin_amdgcn_mfma_f32_16x16x32_bf16(
              af[mf][kk], bg[nf][kk], acc[mf + 4][nf], 0, 0, 0);
    __builtin_amdgcn_s_setprio(0);

    // tile boundary: all of tile t+1's stages (issued phases 0-1, >=2.5
    // phases old) must be LDS-resident & visible to every wave.
    asm volatile("s_waitcnt vmcnt(0)" ::: "memory");
    __builtin_amdgcn_sched_barrier(0);
    __builtin_amdgcn_s_barrier();
  }

  // epilogue: C/D layout col = lane&15, row = (lane>>4)*4 + j  (m89/m91)
#pragma unroll
  for (int mf = 0; mf < 8; ++mf) {
#pragma unroll
    for (int j = 0; j < 4; ++j) {
      const int orow = brow + wr * 128 + mf * 16 + fq * 4 + j;
      float bvv = 0.f;
      if (HAS_BIAS) bvv = bias[orow];
#pragma unroll
      for (int nf = 0; nf < 4; ++nf) {
        const int ocol = bcol + wc * 64 + nf * 16 + fr;
        st(&C[(size_t)orow * ldc + ocol], acc[mf][nf][j] * scale + bvv);
      }
    }
  }
}

extern "C" void kernel_launch(void* const* d_in, const int* in_sizes, int n_in,
                              void* d_out, int out_size, void* d_ws, size_t ws_size,
                              hipStream_t stream) {
  const float* tokens = (const float*)d_in[0];
  const float* Wq = (const float*)d_in[1];
  const float* bq = (const float*)d_in[2];
  const float* Wk = (const float*)d_in[3];
  const float* bk = (const float*)d_in[4];
  const float* Wv = (const float*)d_in[5];
  const float* bv = (const float*)d_in[6];
  const float* Wo = (const float*)d_in[7];
  const float* bo = (const float*)d_in[8];
  float* out = (float*)d_out;
  char* ws = (char*)d_ws;
  const size_t MB = 1024ull * 1024ull;
  // workspace layout (peak 180 MB with slot reuse)
  bf16_t* tT = (bf16_t*)(ws + 0);         // tokensT  4 MB   [0,4)
  bf16_t* Wb = (bf16_t*)(ws + 4 * MB);    // weight slot 16 MB [4,20)
  bf16_t* Qm = (bf16_t*)(ws + 20 * MB);   // 32 MB [20,52)
  bf16_t* Km = (bf16_t*)(ws + 52 * MB);   // 32 MB [52,84)
  bf16_t* Vm = (bf16_t*)(ws + 84 * MB);   // 32 MB [84,116)
  bf16_t* Sb = (bf16_t*)(ws + 116 * MB);  // scores/attn 64 MB [116,180)
  bf16_t* Vs = (bf16_t*)(ws + 20 * MB);   // Vsplit 32 MB (reuse Qm after scores)
  bf16_t* cT = (bf16_t*)(ws + 52 * MB);   // ctxT  32 MB (reuse Km after scores)
  float* Pp = (float*)(ws + 116 * MB);    // split-K partials 64 MB (reuse Sb after ctx)

  dim3 b256(256);
  dim3 b512(512);
  const int nW = HDIM * DMODEL;  // 8388608

  // tokens -> tokensT (bf16)
  transpose_cvt<<<dim3(SEQL / 32, DMODEL / 32), dim3(32, 8), 0, stream>>>(tokens, tT);

  // Q projection: Qm = Wq · tokensT^T + bq   (M=8192,N=2048,K=1024)
  cvt_f32_bf16<<<nW / 1024, b256, 0, stream>>>(Wq, Wb, nW);
  gemm256<bf16_t, true><<<dim3(32 * 8, 1, 1), b512, 0, stream>>>(
      Wb, tT, Qm, bq, HDIM, SEQL, DMODEL, DMODEL, DMODEL, SEQL, 0, 0, 0, 1.0f, 8);
  // K projection
  cvt_f32_bf16<<<nW / 1024, b256, 0, stream>>>(Wk, Wb, nW);
  gemm256<bf16_t, true><<<dim3(32 * 8, 1, 1), b512, 0, stream>>>(
      Wb, tT, Km, bk, HDIM, SEQL, DMODEL, DMODEL, DMODEL, SEQL, 0, 0, 0, 1.0f, 8);
  // V projection
  cvt_f32_bf16<<<nW / 1024, b256, 0, stream>>>(Wv, Wb, nW);
  gemm256<bf16_t, true><<<dim3(32 * 8, 1, 1), b512, 0, stream>>>(
      Wb, tT, Vm, bv, HDIM, SEQL, DMODEL, DMODEL, DMODEL, SEQL, 0, 0, 0, 1.0f, 8);

  // scores[h][l,m] = (1/32) dot(Qm[l*8192 + h*1024 + :], Km[m*8192 + h*1024 + :])
  gemm256<bf16_t, false><<<dim3(8 * 8, 1, 8), b512, 0, stream>>>(
      Qm, Km, Sb, nullptr, SEQL, SEQL, DMODEL, HDIM, HDIM, SEQL,
      1024, 1024, (long long)SEQL * SEQL, 0.03125f, 8);

  // softmax over heads (dim 0), in place
  softmax_heads<<<(SEQL * SEQL / 8) / 256, b256, 0, stream>>>(Sb);

  // Vsplit gather
  vsplit_k<<<dim3(SEQL / 32, DMODEL / 32, 8), dim3(32, 8), 0, stream>>>(Vm, Vs);

  // ctxT[l, h*1024+d] = sum_m attn[h][l,m] * Vsplit[h][d,m]  (M=2048,N=1024,K=2048)
  gemm256<bf16_t, false><<<dim3(8 * 4, 1, 8), b512, 0, stream>>>(
      Sb, Vs, cT, nullptr, SEQL, DMODEL, SEQL, SEQL, SEQL, HDIM,
      (long long)SEQL * SEQL, (long long)DMODEL * SEQL, DMODEL, 1.0f, 4);

  // out = Wo · ctxT^T + bo  (f32 output), split-K=8 over K=8192
  cvt_f32_bf16<<<nW / 1024, b256, 0, stream>>>(Wo, Wb, nW);
  gemm256<float, false><<<dim3(4 * 8, 1, 8), b512, 0, stream>>>(
      Wb, cT, Pp, nullptr, DMODEL, SEQL, 1024, HDIM, HDIM, SEQL,
      1024, 1024, (long long)DMODEL * SEQL, 1.0f, 8);
  reduce_out<<<(DMODEL * SEQL / 4) / 256, b256, 0, stream>>>(Pp, bo, out);
}

// Round 7
// 470.280 us; speedup vs baseline: 1.0428x; 1.0428x over previous
//
#include <hip/hip_runtime.h>

#define SEQL 2048
#define DMODEL 1024
#define HDIM 8192  // H*D

typedef unsigned short bf16_t;
typedef __attribute__((ext_vector_type(8))) short bf16x8;
typedef __attribute__((ext_vector_type(4))) float f32x4;

__device__ __forceinline__ bf16_t f2bf(float f) {
  unsigned u = __float_as_uint(f);
  u += 0x7fffu + ((u >> 16) & 1u);  // RNE
  return (bf16_t)(u >> 16);
}
__device__ __forceinline__ float bf2f(bf16_t b) {
  return __uint_as_float(((unsigned)b) << 16);
}
__device__ __forceinline__ void st(bf16_t* p, float v) { *p = f2bf(v); }
__device__ __forceinline__ void st(float* p, float v) { *p = v; }

// ---------------- elementwise f32 -> bf16 ----------------
__global__ __launch_bounds__(256) void cvt_f32_bf16(const float* __restrict__ in,
                                                    bf16_t* __restrict__ out, int n) {
  int i = (blockIdx.x * 256 + threadIdx.x) * 4;
  if (i >= n) return;
  float4 f = *reinterpret_cast<const float4*>(in + i);
  ushort4 u;
  u.x = f2bf(f.x); u.y = f2bf(f.y); u.z = f2bf(f.z); u.w = f2bf(f.w);
  *reinterpret_cast<ushort4*>(out + i) = u;
}

// tokens (DMODEL x SEQL) f32 -> tokensT (SEQL x DMODEL) bf16
__global__ __launch_bounds__(256) void transpose_cvt(const float* __restrict__ in,
                                                     bf16_t* __restrict__ out) {
  __shared__ float tile[32][33];
  int bx = blockIdx.x * 32;  // seq j
  int by = blockIdx.y * 32;  // channel c
  int tx = threadIdx.x, ty = threadIdx.y;
#pragma unroll
  for (int i = ty; i < 32; i += 8)
    tile[i][tx] = in[(size_t)(by + i) * SEQL + bx + tx];
  __syncthreads();
#pragma unroll
  for (int i = ty; i < 32; i += 8)
    out[(size_t)(bx + i) * DMODEL + by + tx] = f2bf(tile[tx][i]);
}

// Vsplit[h][d][m] = Vm[4m+h2, r*1024+d]  (h = 2*h2 + r), bf16 -> bf16
__global__ __launch_bounds__(256) void vsplit_k(const bf16_t* __restrict__ Vm,
                                                bf16_t* __restrict__ Vs) {
  __shared__ bf16_t tile[32][33];
  int h = blockIdx.z, h2 = h >> 1, r = h & 1;
  int m0 = blockIdx.x * 32, d0 = blockIdx.y * 32;
  int tx = threadIdx.x, ty = threadIdx.y;
#pragma unroll
  for (int i = ty; i < 32; i += 8)  // i: m offset, tx: d offset
    tile[i][tx] = Vm[(size_t)(4 * (m0 + i) + h2) * SEQL + r * DMODEL + d0 + tx];
  __syncthreads();
#pragma unroll
  for (int i = ty; i < 32; i += 8)  // i: d offset, tx: m offset
    Vs[((size_t)h * DMODEL + d0 + i) * SEQL + m0 + tx] = tile[tx][i];
}

// softmax over the 8 heads (dim 0), in place on bf16 S[8][L*L]
__global__ __launch_bounds__(256) void softmax_heads(bf16_t* __restrict__ S) {
  const size_t HS = (size_t)SEQL * SEQL;
  size_t p = ((size_t)blockIdx.x * 256 + threadIdx.x) * 8;
  float v[8][8];
#pragma unroll
  for (int h = 0; h < 8; ++h) {
    bf16x8 x = *reinterpret_cast<const bf16x8*>(S + h * HS + p);
#pragma unroll
    for (int e = 0; e < 8; ++e) v[h][e] = bf2f((bf16_t)x[e]);
  }
#pragma unroll
  for (int e = 0; e < 8; ++e) {
    float mx = v[0][e];
#pragma unroll
    for (int h = 1; h < 8; ++h) mx = fmaxf(mx, v[h][e]);
    float s = 0.f;
#pragma unroll
    for (int h = 0; h < 8; ++h) { v[h][e] = __expf(v[h][e] - mx); s += v[h][e]; }
    float inv = 1.0f / s;
#pragma unroll
    for (int h = 0; h < 8; ++h) v[h][e] *= inv;
  }
#pragma unroll
  for (int h = 0; h < 8; ++h) {
    bf16x8 x;
#pragma unroll
    for (int e = 0; e < 8; ++e) x[e] = (short)f2bf(v[h][e]);
    *reinterpret_cast<bf16x8*>(S + h * HS + p) = x;
  }
}

// reduce 8 f32 split-K partials P[z][D][L] -> out[D][L] + bias[row]
__global__ __launch_bounds__(256) void reduce_out(const float* __restrict__ P,
                                                  const float* __restrict__ bo,
                                                  float* __restrict__ out) {
  const size_t NEL = (size_t)DMODEL * SEQL;
  size_t i = ((size_t)blockIdx.x * 256 + threadIdx.x) * 4;
  float4 a = *reinterpret_cast<const float4*>(P + i);
#pragma unroll
  for (int z = 1; z < 8; ++z) {
    float4 b = *reinterpret_cast<const float4*>(P + z * NEL + i);
    a.x += b.x; a.y += b.y; a.z += b.z; a.w += b.w;
  }
  float bias = bo[i / SEQL];
  a.x += bias; a.y += bias; a.z += bias; a.w += bias;
  *reinterpret_cast<float4*>(out + i) = a;
}

// ---------------- C = scale * A·B^T (+bias[row]), 256x256 tile ----------------
// A: M x K (row stride lda), B: N x K (row stride ldb), bf16 K-contiguous.
// 512 threads = 8 waves (2M x 4N); per-wave output 128x64 = 8x4 frags of
// 16x16; BK=32 (one MFMA k-step); 32 MFMA / wave / K-tile, free-run body.
// TRIPLE-buffered K-pipeline with COUNTED vmcnt (T3+T4; R3-validated sync
// pattern on this pipeline depth):
//   tile t: STAGE(tile t+2, 4 loads/thread) -> ds_read 12 frags -> 32 MFMA
//           -> sched_barrier -> s_waitcnt vmcnt(4) [newest stage stays in
//           flight; tile t+1's loads (2 tiles old) are guaranteed landed]
//           -> s_barrier -> sched_barrier.
// Never drains vmcnt to 0 in the main loop (epilogue tiles use vmcnt(0)).
// WAR: tile t's ds_reads are consumed by tile t's MFMAs before its boundary
// barrier, so STAGE into buf[(t+2)%3] (= buffer read in tile t-1, two
// barriers ago) is safe. RAW: staging wave's vmcnt retires its LDS writes
// before its barrier; readers start after the barrier. All waits are asm
// with memory clobber; sched_barrier(0) seals tile bodies (rule 18).
// 4-slot XOR swizzle both sides (rule #21): phys slot s of row r holds
// global k-chunk s ^ ((r>>1)&3); global_load_lds dest linear, source
// pre-swizzled -> 2-way bank aliasing (free, measured 0 conflicts).
// Grid 1D per z-slice, XCD-chunked swizzle (T1), nwg % 8 == 0.
template <typename OutT, bool HAS_BIAS>
__global__ __launch_bounds__(512, 2) void gemm256(
    const bf16_t* __restrict__ A, const bf16_t* __restrict__ B,
    OutT* __restrict__ C, const float* __restrict__ bias,
    int M, int N, int K, int lda, int ldb, int ldc,
    long long sA, long long sB, long long sC, float scale, int gx) {
  __shared__ alignas(16) bf16_t As[3][256 * 32];
  __shared__ alignas(16) bf16_t Bs[3][256 * 32];
  const int z = blockIdx.z;
  A += (long long)z * sA;
  B += (long long)z * sB;
  C += (long long)z * sC;
  const int nwg = gridDim.x;
  const int bid = blockIdx.x;
  const int swz = (nwg & 7) ? bid : ((bid & 7) * (nwg >> 3) + (bid >> 3));
  const int brow = (swz / gx) * 256;
  const int bcol = (swz % gx) * 256;
  const int tid = threadIdx.x;
  const int w = tid >> 6, lane = tid & 63;
  const int fr = lane & 15, fq = lane >> 4;
  const int wr = w >> 2, wc = w & 3;

  // staging map: 256x32 tile = 16KB = 1024 chunks of 16B; thread covers
  // chunks c = w*128 + j*64 + lane (j=0,1) for A and the same for B.
  // row = c>>2 (4 chunks/row); phys slot c&3 holds global k-chunk
  // (c&3) ^ ((row>>1)&3).
  int rw[2], co[2];
#pragma unroll
  for (int j = 0; j < 2; ++j) {
    const int c = w * 128 + j * 64 + lane;
    rw[j] = c >> 2;
    co[j] = ((c & 3) ^ ((rw[j] >> 1) & 3)) << 3;
  }

  auto STAGE = [&](int buf, int kk) {
#pragma unroll
    for (int j = 0; j < 2; ++j) {
      const bf16_t* g = A + (size_t)(brow + rw[j]) * lda + kk + co[j];
      __builtin_amdgcn_global_load_lds(
          (const __attribute__((address_space(1))) void*)g,
          (__attribute__((address_space(3))) void*)(&As[buf][w * 1024 + j * 512]),
          16, 0, 0);
    }
#pragma unroll
    for (int j = 0; j < 2; ++j) {
      const bf16_t* g = B + (size_t)(bcol + rw[j]) * ldb + kk + co[j];
      __builtin_amdgcn_global_load_lds(
          (const __attribute__((address_space(1))) void*)g,
          (__attribute__((address_space(3))) void*)(&Bs[buf][w * 1024 + j * 512]),
          16, 0, 0);
    }
  };

  // fragment reads (swizzled): logical k-chunk fq of row rr is at phys slot
  // fq ^ ((rr>>1)&3).
  auto ldA = [&](int buf, int mf) -> bf16x8 {
    const int rr = wr * 128 + mf * 16 + fr;
    return *reinterpret_cast<const bf16x8*>(
        &As[buf][rr * 32 + ((fq ^ ((rr >> 1) & 3)) << 3)]);
  };
  auto ldB = [&](int buf, int nf) -> bf16x8 {
    const int rr = wc * 64 + nf * 16 + fr;
    return *reinterpret_cast<const bf16x8*>(
        &Bs[buf][rr * 32 + ((fq ^ ((rr >> 1) & 3)) << 3)]);
  };

  f32x4 acc[8][4];
  const f32x4 fzero = {0.f, 0.f, 0.f, 0.f};
#pragma unroll
  for (int m = 0; m < 8; ++m)
#pragma unroll
    for (int n = 0; n < 4; ++n) acc[m][n] = fzero;

  const int NT = K >> 5;  // K % 32 == 0, NT >= 3 at all call sites

  // prologue: stage tiles 0 and 1; wait for tile 0 (newest 4 may fly)
  STAGE(0, 0);
  STAGE(1, 32);
  asm volatile("s_waitcnt vmcnt(4)" ::: "memory");
  __builtin_amdgcn_sched_barrier(0);
  __builtin_amdgcn_s_barrier();
  __builtin_amdgcn_sched_barrier(0);

  int p = 0;  // buffer of tile t
  for (int t = 0; t < NT; ++t) {
    int sb = p + 2; if (sb >= 3) sb -= 3;
    const bool pre = (t + 2 < NT);
    if (pre) STAGE(sb, (t + 2) << 5);

    bf16x8 af[8], bg[4];
#pragma unroll
    for (int mf = 0; mf < 8; ++mf) af[mf] = ldA(p, mf);
#pragma unroll
    for (int nf = 0; nf < 4; ++nf) bg[nf] = ldB(p, nf);
    __builtin_amdgcn_s_setprio(1);
#pragma unroll
    for (int mf = 0; mf < 8; ++mf)
#pragma unroll
      for (int nf = 0; nf < 4; ++nf)
        acc[mf][nf] = __builtin_amdgcn_mfma_f32_16x16x32_bf16(
            af[mf], bg[nf], acc[mf][nf], 0, 0, 0);
    __builtin_amdgcn_s_setprio(0);

    // boundary: tile t+1 (staged 2 tiles ago) must be resident; keep the
    // newest stage (tile t+2) in flight. Epilogue tiles drain fully.
    __builtin_amdgcn_sched_barrier(0);
    if (pre) {
      asm volatile("s_waitcnt vmcnt(4)" ::: "memory");
    } else {
      asm volatile("s_waitcnt vmcnt(0)" ::: "memory");
    }
    __builtin_amdgcn_sched_barrier(0);
    __builtin_amdgcn_s_barrier();
    __builtin_amdgcn_sched_barrier(0);

    ++p; if (p >= 3) p = 0;
  }

  // epilogue: C/D layout col = lane&15, row = (lane>>4)*4 + j  (m89/m91)
#pragma unroll
  for (int mf = 0; mf < 8; ++mf) {
#pragma unroll
    for (int j = 0; j < 4; ++j) {
      const int orow = brow + wr * 128 + mf * 16 + fq * 4 + j;
      float bvv = 0.f;
      if (HAS_BIAS) bvv = bias[orow];
#pragma unroll
      for (int nf = 0; nf < 4; ++nf) {
        const int ocol = bcol + wc * 64 + nf * 16 + fr;
        st(&C[(size_t)orow * ldc + ocol], acc[mf][nf][j] * scale + bvv);
      }
    }
  }
}

extern "C" void kernel_launch(void* const* d_in, const int* in_sizes, int n_in,
                              void* d_out, int out_size, void* d_ws, size_t ws_size,
                              hipStream_t stream) {
  const float* tokens = (const float*)d_in[0];
  const float* Wq = (const float*)d_in[1];
  const float* bq = (const float*)d_in[2];
  const float* Wk = (const float*)d_in[3];
  const float* bk = (const float*)d_in[4];
  const float* Wv = (const float*)d_in[5];
  const float* bv = (const float*)d_in[6];
  const float* Wo = (const float*)d_in[7];
  const float* bo = (const float*)d_in[8];
  float* out = (float*)d_out;
  char* ws = (char*)d_ws;
  const size_t MB = 1024ull * 1024ull;
  // workspace layout (peak 180 MB with slot reuse)
  bf16_t* tT = (bf16_t*)(ws + 0);         // tokensT  4 MB   [0,4)
  bf16_t* Wb = (bf16_t*)(ws + 4 * MB);    // weight slot 16 MB [4,20)
  bf16_t* Qm = (bf16_t*)(ws + 20 * MB);   // 32 MB [20,52)
  bf16_t* Km = (bf16_t*)(ws + 52 * MB);   // 32 MB [52,84)
  bf16_t* Vm = (bf16_t*)(ws + 84 * MB);   // 32 MB [84,116)
  bf16_t* Sb = (bf16_t*)(ws + 116 * MB);  // scores/attn 64 MB [116,180)
  bf16_t* Vs = (bf16_t*)(ws + 20 * MB);   // Vsplit 32 MB (reuse Qm after scores)
  bf16_t* cT = (bf16_t*)(ws + 52 * MB);   // ctxT  32 MB (reuse Km after scores)
  float* Pp = (float*)(ws + 116 * MB);    // split-K partials 64 MB (reuse Sb after ctx)

  dim3 b256(256);
  dim3 b512(512);
  const int nW = HDIM * DMODEL;  // 8388608

  // tokens -> tokensT (bf16)
  transpose_cvt<<<dim3(SEQL / 32, DMODEL / 32), dim3(32, 8), 0, stream>>>(tokens, tT);

  // Q projection: Qm = Wq · tokensT^T + bq   (M=8192,N=2048,K=1024)
  cvt_f32_bf16<<<nW / 1024, b256, 0, stream>>>(Wq, Wb, nW);
  gemm256<bf16_t, true><<<dim3(32 * 8, 1, 1), b512, 0, stream>>>(
      Wb, tT, Qm, bq, HDIM, SEQL, DMODEL, DMODEL, DMODEL, SEQL, 0, 0, 0, 1.0f, 8);
  // K projection
  cvt_f32_bf16<<<nW / 1024, b256, 0, stream>>>(Wk, Wb, nW);
  gemm256<bf16_t, true><<<dim3(32 * 8, 1, 1), b512, 0, stream>>>(
      Wb, tT, Km, bk, HDIM, SEQL, DMODEL, DMODEL, DMODEL, SEQL, 0, 0, 0, 1.0f, 8);
  // V projection
  cvt_f32_bf16<<<nW / 1024, b256, 0, stream>>>(Wv, Wb, nW);
  gemm256<bf16_t, true><<<dim3(32 * 8, 1, 1), b512, 0, stream>>>(
      Wb, tT, Vm, bv, HDIM, SEQL, DMODEL, DMODEL, DMODEL, SEQL, 0, 0, 0, 1.0f, 8);

  // scores[h][l,m] = (1/32) dot(Qm[l*8192 + h*1024 + :], Km[m*8192 + h*1024 + :])
  gemm256<bf16_t, false><<<dim3(8 * 8, 1, 8), b512, 0, stream>>>(
      Qm, Km, Sb, nullptr, SEQL, SEQL, DMODEL, HDIM, HDIM, SEQL,
      1024, 1024, (long long)SEQL * SEQL, 0.03125f, 8);

  // softmax over heads (dim 0), in place
  softmax_heads<<<(SEQL * SEQL / 8) / 256, b256, 0, stream>>>(Sb);

  // Vsplit gather
  vsplit_k<<<dim3(SEQL / 32, DMODEL / 32, 8), dim3(32, 8), 0, stream>>>(Vm, Vs);

  // ctxT[l, h*1024+d] = sum_m attn[h][l,m] * Vsplit[h][d,m]  (M=2048,N=1024,K=2048)
  gemm256<bf16_t, false><<<dim3(8 * 4, 1, 8), b512, 0, stream>>>(
      Sb, Vs, cT, nullptr, SEQL, DMODEL, SEQL, SEQL, SEQL, HDIM,
      (long long)SEQL * SEQL, (long long)DMODEL * SEQL, DMODEL, 1.0f, 4);

  // out = Wo · ctxT^T + bo  (f32 output), split-K=8 over K=8192
  cvt_f32_bf16<<<nW / 1024, b256, 0, stream>>>(Wo, Wb, nW);
  gemm256<float, false><<<dim3(4 * 8, 1, 8), b512, 0, stream>>>(
      Wb, cT, Pp, nullptr, DMODEL, SEQL, 1024, HDIM, HDIM, SEQL,
      1024, 1024, (long long)DMODEL * SEQL, 1.0f, 8);
  reduce_out<<<(DMODEL * SEQL / 4) / 256, b256, 0, stream>>>(Pp, bo, out);
}

// Round 8
// 369.212 us; speedup vs baseline: 1.3283x; 1.2737x over previous
//
#include <hip/hip_runtime.h>

#define SEQL 2048
#define DMODEL 1024
#define HDIM 8192  // H*D

typedef unsigned short bf16_t;
typedef __attribute__((ext_vector_type(8))) short bf16x8;
typedef __attribute__((ext_vector_type(4))) float f32x4;

__device__ __forceinline__ bf16_t f2bf(float f) {
  unsigned u = __float_as_uint(f);
  u += 0x7fffu + ((u >> 16) & 1u);  // RNE
  return (bf16_t)(u >> 16);
}
__device__ __forceinline__ float bf2f(bf16_t b) {
  return __uint_as_float(((unsigned)b) << 16);
}

// ---------------- elementwise f32 -> bf16 ----------------
__global__ __launch_bounds__(256) void cvt_f32_bf16(const float* __restrict__ in,
                                                    bf16_t* __restrict__ out, int n) {
  int i = (blockIdx.x * 256 + threadIdx.x) * 4;
  if (i >= n) return;
  float4 f = *reinterpret_cast<const float4*>(in + i);
  ushort4 u;
  u.x = f2bf(f.x); u.y = f2bf(f.y); u.z = f2bf(f.z); u.w = f2bf(f.w);
  *reinterpret_cast<ushort4*>(out + i) = u;
}

// tokens (DMODEL x SEQL) f32 -> tokensT (SEQL x DMODEL) bf16
__global__ __launch_bounds__(256) void transpose_cvt(const float* __restrict__ in,
                                                     bf16_t* __restrict__ out) {
  __shared__ float tile[32][33];
  int bx = blockIdx.x * 32;  // seq j
  int by = blockIdx.y * 32;  // channel c
  int tx = threadIdx.x, ty = threadIdx.y;
#pragma unroll
  for (int i = ty; i < 32; i += 8)
    tile[i][tx] = in[(size_t)(by + i) * SEQL + bx + tx];
  __syncthreads();
#pragma unroll
  for (int i = ty; i < 32; i += 8)
    out[(size_t)(bx + i) * DMODEL + by + tx] = f2bf(tile[tx][i]);
}

// softmax over the 8 heads (dim 0), in place on bf16 S[8][L*L]
__global__ __launch_bounds__(256) void softmax_heads(bf16_t* __restrict__ S) {
  const size_t HS = (size_t)SEQL * SEQL;
  size_t p = ((size_t)blockIdx.x * 256 + threadIdx.x) * 8;
  float v[8][8];
#pragma unroll
  for (int h = 0; h < 8; ++h) {
    bf16x8 x = *reinterpret_cast<const bf16x8*>(S + h * HS + p);
#pragma unroll
    for (int e = 0; e < 8; ++e) v[h][e] = bf2f((bf16_t)x[e]);
  }
#pragma unroll
  for (int e = 0; e < 8; ++e) {
    float mx = v[0][e];
#pragma unroll
    for (int h = 1; h < 8; ++h) mx = fmaxf(mx, v[h][e]);
    float s = 0.f;
#pragma unroll
    for (int h = 0; h < 8; ++h) { v[h][e] = __expf(v[h][e] - mx); s += v[h][e]; }
    float inv = 1.0f / s;
#pragma unroll
    for (int h = 0; h < 8; ++h) v[h][e] *= inv;
  }
#pragma unroll
  for (int h = 0; h < 8; ++h) {
    bf16x8 x;
#pragma unroll
    for (int e = 0; e < 8; ++e) x[e] = (short)f2bf(v[h][e]);
    *reinterpret_cast<bf16x8*>(S + h * HS + p) = x;
  }
}

// reduce 8 f32 split-K partials P[z][D][L] -> out[D][L] + bias[row]
__global__ __launch_bounds__(256) void reduce_out(const float* __restrict__ P,
                                                  const float* __restrict__ bo,
                                                  float* __restrict__ out) {
  const size_t NEL = (size_t)DMODEL * SEQL;
  size_t i = ((size_t)blockIdx.x * 256 + threadIdx.x) * 4;
  float4 a = *reinterpret_cast<const float4*>(P + i);
#pragma unroll
  for (int z = 1; z < 8; ++z) {
    float4 b = *reinterpret_cast<const float4*>(P + z * NEL + i);
    a.x += b.x; a.y += b.y; a.z += b.z; a.w += b.w;
  }
  float bias = bo[i / SEQL];
  a.x += bias; a.y += bias; a.z += bias; a.w += bias;
  *reinterpret_cast<float4*>(out + i) = a;
}

// ---------------- C = scale * A·B^T (+bias[row]), 256x256 tile ----------------
// R5 core (best measured): 512 thr = 8 waves (2M x 4N), BK=64, double-buffered
// LDS, 4 free-run MFMA groups per K-tile with stages interleaved in groups
// 0-1, one __syncthreads per tile boundary. 8-slot XOR swizzle both sides
// (rule #21) -> conflict-free ds_read_b128 (measured 0).
// NEW: coalesced epilogues via LDS C-staging (fixes the measured 1.96x
// write amplification from scattered 2B stores):
//   EPI 0 (bf16): acc -> LDS [256][264] bf16 -> b128 reads -> 16B stores.
//   EPI 1 (f32):  two halves (wr=0 rows then wr=1) [128][264] f32.
//   EPI 2 (VSPLIT): write V projection directly in Vs[h][d][m] layout:
//     g=brow+i, l=bcol+j maps to h=2*(g&3)+(l>>10), d=l&1023, m=g>>2.
//     acc -> LDS [4][256][72] (h2,dloc,mloc), then 128B-contiguous stores.
//     Eliminates the separate vsplit pass (64 MB RW).
// Grid 1D per z-slice, XCD-chunked bijective swizzle (T1), nwg % 8 == 0.
template <typename OutT, int EPI, bool HAS_BIAS>
__global__ __launch_bounds__(512, 2) void gemm256(
    const bf16_t* __restrict__ A, const bf16_t* __restrict__ B,
    OutT* __restrict__ C, const float* __restrict__ bias,
    int M, int N, int K, int lda, int ldb, int ldc,
    long long sA, long long sB, long long sC, float scale, int gx) {
  __shared__ alignas(16) char smem[147456];  // 144 KB arena
  auto* As = reinterpret_cast<bf16_t(*)[2][8192]>(smem);            // [buf][half][128*64]
  auto* Bs = reinterpret_cast<bf16_t(*)[2][8192]>(smem + 65536);
  const int z = blockIdx.z;
  A += (long long)z * sA;
  B += (long long)z * sB;
  C += (long long)z * sC;
  const int nwg = gridDim.x;
  const int bid = blockIdx.x;
  const int swz = (nwg & 7) ? bid : ((bid & 7) * (nwg >> 3) + (bid >> 3));
  const int brow = (swz / gx) * 256;
  const int bcol = (swz % gx) * 256;
  const int tid = threadIdx.x;
  const int w = tid >> 6, lane = tid & 63;
  const int fr = lane & 15, fq = lane >> 4;
  const int wr = w >> 2, wc = w & 3;

  int rj[2], cj[2];
#pragma unroll
  for (int j = 0; j < 2; ++j) {
    const int c = (w * 2 + j) * 64 + lane;
    rj[j] = c >> 3;
    cj[j] = ((c & 7) ^ (rj[j] & 7)) << 3;
  }

  auto stageA = [&](int buf, int half, int kk) {
#pragma unroll
    for (int j = 0; j < 2; ++j) {
      const bf16_t* g = A + (size_t)(brow + half * 128 + rj[j]) * lda + kk + cj[j];
      __builtin_amdgcn_global_load_lds(
          (const __attribute__((address_space(1))) void*)g,
          (__attribute__((address_space(3))) void*)(&As[buf][half][(w * 2 + j) * 512]),
          16, 0, 0);
    }
  };
  auto stageB = [&](int buf, int half, int kk) {
#pragma unroll
    for (int j = 0; j < 2; ++j) {
      const bf16_t* g = B + (size_t)(bcol + half * 128 + rj[j]) * ldb + kk + cj[j];
      __builtin_amdgcn_global_load_lds(
          (const __attribute__((address_space(1))) void*)g,
          (__attribute__((address_space(3))) void*)(&Bs[buf][half][(w * 2 + j) * 512]),
          16, 0, 0);
    }
  };

  auto ldA = [&](int buf, int mf, int kk) -> bf16x8 {
    const int rr = mf * 16 + fr;
    return *reinterpret_cast<const bf16x8*>(
        &As[buf][wr][rr * 64 + ((((kk << 2) | fq) ^ (rr & 7)) << 3)]);
  };
  auto ldB = [&](int buf, int nf, int kk) -> bf16x8 {
    const int rr = (wc & 1) * 64 + nf * 16 + fr;
    return *reinterpret_cast<const bf16x8*>(
        &Bs[buf][wc >> 1][rr * 64 + ((((kk << 2) | fq) ^ (rr & 7)) << 3)]);
  };

  f32x4 acc[8][4];
  const f32x4 fzero = {0.f, 0.f, 0.f, 0.f};
#pragma unroll
  for (int m = 0; m < 8; ++m)
#pragma unroll
    for (int n = 0; n < 4; ++n) acc[m][n] = fzero;

  const int NT = K >> 6;  // K % 64 == 0, NT >= 2 at all call sites
  stageA(0, 0, 0); stageA(0, 1, 0); stageB(0, 0, 0); stageB(0, 1, 0);
  __syncthreads();

  for (int t = 0; t < NT; ++t) {
    const int p = t & 1, q = p ^ 1;
    const int kn = (t + 1) << 6;
    const bool pre = (t + 1 < NT);
    bf16x8 af[4][2], bg[4][2];

    // ---- group 0: rows 0-63 x cols 0-31 ----
    if (pre) { stageA(q, 0, kn); stageA(q, 1, kn); }
#pragma unroll
    for (int mf = 0; mf < 4; ++mf)
#pragma unroll
      for (int kk = 0; kk < 2; ++kk) af[mf][kk] = ldA(p, mf, kk);
#pragma unroll
    for (int nf = 0; nf < 2; ++nf)
#pragma unroll
      for (int kk = 0; kk < 2; ++kk) bg[nf][kk] = ldB(p, nf, kk);
    __builtin_amdgcn_s_setprio(1);
#pragma unroll
    for (int mf = 0; mf < 4; ++mf)
#pragma unroll
      for (int nf = 0; nf < 2; ++nf)
#pragma unroll
        for (int kk = 0; kk < 2; ++kk)
          acc[mf][nf] = __builtin_amdgcn_mfma_f32_16x16x32_bf16(
              af[mf][kk], bg[nf][kk], acc[mf][nf], 0, 0, 0);
    __builtin_amdgcn_s_setprio(0);

    // ---- group 1: rows 0-63 x cols 32-63 ----
    if (pre) { stageB(q, 0, kn); stageB(q, 1, kn); }
#pragma unroll
    for (int nf = 2; nf < 4; ++nf)
#pragma unroll
      for (int kk = 0; kk < 2; ++kk) bg[nf][kk] = ldB(p, nf, kk);
    __builtin_amdgcn_s_setprio(1);
#pragma unroll
    for (int mf = 0; mf < 4; ++mf)
#pragma unroll
      for (int nf = 2; nf < 4; ++nf)
#pragma unroll
        for (int kk = 0; kk < 2; ++kk)
          acc[mf][nf] = __builtin_amdgcn_mfma_f32_16x16x32_bf16(
              af[mf][kk], bg[nf][kk], acc[mf][nf], 0, 0, 0);
    __builtin_amdgcn_s_setprio(0);

    // ---- group 2: rows 64-127 x cols 32-63 ----
#pragma unroll
    for (int mf = 0; mf < 4; ++mf)
#pragma unroll
      for (int kk = 0; kk < 2; ++kk) af[mf][kk] = ldA(p, mf + 4, kk);
    __builtin_amdgcn_s_setprio(1);
#pragma unroll
    for (int mf = 0; mf < 4; ++mf)
#pragma unroll
      for (int nf = 2; nf < 4; ++nf)
#pragma unroll
        for (int kk = 0; kk < 2; ++kk)
          acc[mf + 4][nf] = __builtin_amdgcn_mfma_f32_16x16x32_bf16(
              af[mf][kk], bg[nf][kk], acc[mf + 4][nf], 0, 0, 0);
    __builtin_amdgcn_s_setprio(0);

    // ---- group 3: rows 64-127 x cols 0-31 ----
#pragma unroll
    for (int nf = 0; nf < 2; ++nf)
#pragma unroll
      for (int kk = 0; kk < 2; ++kk) bg[nf][kk] = ldB(p, nf, kk);
    __builtin_amdgcn_s_setprio(1);
#pragma unroll
    for (int mf = 0; mf < 4; ++mf)
#pragma unroll
      for (int nf = 0; nf < 2; ++nf)
#pragma unroll
        for (int kk = 0; kk < 2; ++kk)
          acc[mf + 4][nf] = __builtin_amdgcn_mfma_f32_16x16x32_bf16(
              af[mf][kk], bg[nf][kk], acc[mf + 4][nf], 0, 0, 0);
    __builtin_amdgcn_s_setprio(0);

    if (pre) __syncthreads();
  }

  // ======== epilogues (LDS C-staging, coalesced stores) ========
  __syncthreads();  // all waves' LDS reads retired -> arena reusable

  if constexpr (EPI == 0) {  // bf16 C, [256][264] bf16 staging
    bf16_t* Ct = (bf16_t*)smem;
#pragma unroll
    for (int mf = 0; mf < 8; ++mf)
#pragma unroll
      for (int j = 0; j < 4; ++j) {
        const int orow = wr * 128 + mf * 16 + fq * 4 + j;
        float bvv = HAS_BIAS ? bias[brow + orow] : 0.f;
#pragma unroll
        for (int nf = 0; nf < 4; ++nf)
          Ct[orow * 264 + wc * 64 + nf * 16 + fr] = f2bf(acc[mf][nf][j] * scale + bvv);
      }
    __syncthreads();
#pragma unroll
    for (int i = 0; i < 16; ++i) {
      const int c = tid + i * 512;        // 16B chunk id, 8192 total
      const int row = c >> 5, ch = c & 31;
      *reinterpret_cast<bf16x8*>(&C[(size_t)(brow + row) * ldc + bcol + ch * 8]) =
          *reinterpret_cast<const bf16x8*>(smem + row * 528 + ch * 16);
    }
  } else if constexpr (EPI == 1) {  // f32 C, two halves [128][264] f32
    float* Cf = (float*)smem;
#pragma unroll
    for (int h = 0; h < 2; ++h) {
      if (wr == h) {
#pragma unroll
        for (int mf = 0; mf < 8; ++mf)
#pragma unroll
          for (int j = 0; j < 4; ++j) {
            const int orow = mf * 16 + fq * 4 + j;  // 0..127
            float bvv = HAS_BIAS ? bias[brow + h * 128 + orow] : 0.f;
#pragma unroll
            for (int nf = 0; nf < 4; ++nf)
              Cf[orow * 264 + wc * 64 + nf * 16 + fr] = acc[mf][nf][j] * scale + bvv;
          }
      }
      __syncthreads();
#pragma unroll
      for (int i = 0; i < 16; ++i) {
        const int c = tid + i * 512;      // 16B chunk id, 8192 total
        const int row = c >> 6, ch = c & 63;
        *reinterpret_cast<float4*>(&C[(size_t)(brow + h * 128 + row) * ldc + bcol + ch * 4]) =
            *reinterpret_cast<const float4*>(smem + row * 1056 + ch * 16);
      }
      __syncthreads();
    }
  } else {  // EPI == 2: VSPLIT — C points at Vs[8][1024][2048] (bf16)
    bf16_t* Vt = (bf16_t*)smem;  // [4][256][72]: (h2, dloc, mloc)
#pragma unroll
    for (int mf = 0; mf < 8; ++mf)
#pragma unroll
      for (int j = 0; j < 4; ++j) {
        const int i = wr * 128 + mf * 16 + fq * 4 + j;  // g offset; h2 = j
        const int mloc = i >> 2;
        float bvv = HAS_BIAS ? bias[brow + i] : 0.f;
#pragma unroll
        for (int nf = 0; nf < 4; ++nf) {
          const int dloc = wc * 64 + nf * 16 + fr;
          Vt[(j * 256 + dloc) * 72 + mloc] = f2bf(acc[mf][nf][j] * scale + bvv);
        }
      }
    __syncthreads();
    const int r_ = bcol >> 10, d0 = bcol & 1023, m0 = brow >> 2;
#pragma unroll
    for (int sIt = 0; sIt < 2; ++sIt) {
      const int s = tid + sIt * 512;      // seg id: 4 h2 x 256 dloc
      const int h2 = s >> 8, dloc = s & 255;
      const bf16_t* src = Vt + (h2 * 256 + dloc) * 72;
      bf16_t* dst = (bf16_t*)C + ((size_t)(2 * h2 + r_) * DMODEL + d0 + dloc) * SEQL + m0;
#pragma unroll
      for (int qq = 0; qq < 8; ++qq)
        *reinterpret_cast<bf16x8*>(dst + qq * 8) =
            *reinterpret_cast<const bf16x8*>(src + qq * 8);
    }
  }
}

extern "C" void kernel_launch(void* const* d_in, const int* in_sizes, int n_in,
                              void* d_out, int out_size, void* d_ws, size_t ws_size,
                              hipStream_t stream) {
  const float* tokens = (const float*)d_in[0];
  const float* Wq = (const float*)d_in[1];
  const float* bq = (const float*)d_in[2];
  const float* Wk = (const float*)d_in[3];
  const float* bk = (const float*)d_in[4];
  const float* Wv = (const float*)d_in[5];
  const float* bv = (const float*)d_in[6];
  const float* Wo = (const float*)d_in[7];
  const float* bo = (const float*)d_in[8];
  float* out = (float*)d_out;
  char* ws = (char*)d_ws;
  const size_t MB = 1024ull * 1024ull;
  // workspace layout (peak 180 MB)
  bf16_t* tT = (bf16_t*)(ws + 0);         // tokensT  4 MB   [0,4)
  bf16_t* Wb = (bf16_t*)(ws + 4 * MB);    // weight slot 16 MB [4,20)
  bf16_t* Qm = (bf16_t*)(ws + 20 * MB);   // 32 MB [20,52)
  bf16_t* Km = (bf16_t*)(ws + 52 * MB);   // 32 MB [52,84)
  bf16_t* Vs = (bf16_t*)(ws + 84 * MB);   // Vsplit 32 MB [84,116) (written by V-GEMM)
  bf16_t* Sb = (bf16_t*)(ws + 116 * MB);  // scores/attn 64 MB [116,180)
  bf16_t* cT = (bf16_t*)(ws + 20 * MB);   // ctxT 32 MB (reuse Qm after scores)
  float* Pp = (float*)(ws + 116 * MB);    // split-K partials 64 MB (reuse Sb after ctx)

  dim3 b256(256);
  dim3 b512(512);
  const int nW = HDIM * DMODEL;  // 8388608

  // tokens -> tokensT (bf16)
  transpose_cvt<<<dim3(SEQL / 32, DMODEL / 32), dim3(32, 8), 0, stream>>>(tokens, tT);

  // Q projection: Qm = Wq · tokensT^T + bq   (M=8192,N=2048,K=1024)
  cvt_f32_bf16<<<nW / 1024, b256, 0, stream>>>(Wq, Wb, nW);
  gemm256<bf16_t, 0, true><<<dim3(32 * 8, 1, 1), b512, 0, stream>>>(
      Wb, tT, Qm, bq, HDIM, SEQL, DMODEL, DMODEL, DMODEL, SEQL, 0, 0, 0, 1.0f, 8);
  // K projection
  cvt_f32_bf16<<<nW / 1024, b256, 0, stream>>>(Wk, Wb, nW);
  gemm256<bf16_t, 0, true><<<dim3(32 * 8, 1, 1), b512, 0, stream>>>(
      Wb, tT, Km, bk, HDIM, SEQL, DMODEL, DMODEL, DMODEL, SEQL, 0, 0, 0, 1.0f, 8);
  // V projection -> writes Vs[h][d][m] directly (VSPLIT epilogue)
  cvt_f32_bf16<<<nW / 1024, b256, 0, stream>>>(Wv, Wb, nW);
  gemm256<bf16_t, 2, true><<<dim3(32 * 8, 1, 1), b512, 0, stream>>>(
      Wb, tT, Vs, bv, HDIM, SEQL, DMODEL, DMODEL, DMODEL, SEQL, 0, 0, 0, 1.0f, 8);

  // scores[h][l,m] = (1/32) dot(Qm[l*8192 + h*1024 + :], Km[m*8192 + h*1024 + :])
  gemm256<bf16_t, 0, false><<<dim3(8 * 8, 1, 8), b512, 0, stream>>>(
      Qm, Km, Sb, nullptr, SEQL, SEQL, DMODEL, HDIM, HDIM, SEQL,
      1024, 1024, (long long)SEQL * SEQL, 0.03125f, 8);

  // softmax over heads (dim 0), in place
  softmax_heads<<<(SEQL * SEQL / 8) / 256, b256, 0, stream>>>(Sb);

  // ctxT[l, h*1024+d] = sum_m attn[h][l,m] * Vs[h][d,m]  (M=2048,N=1024,K=2048)
  gemm256<bf16_t, 0, false><<<dim3(8 * 4, 1, 8), b512, 0, stream>>>(
      Sb, Vs, cT, nullptr, SEQL, DMODEL, SEQL, SEQL, SEQL, HDIM,
      (long long)SEQL * SEQL, (long long)DMODEL * SEQL, DMODEL, 1.0f, 4);

  // out = Wo · ctxT^T + bo  (f32 output), split-K=8 over K=8192
  cvt_f32_bf16<<<nW / 1024, b256, 0, stream>>>(Wo, Wb, nW);
  gemm256<float, 1, false><<<dim3(4 * 8, 1, 8), b512, 0, stream>>>(
      Wb, cT, Pp, nullptr, DMODEL, SEQL, 1024, HDIM, HDIM, SEQL,
      1024, 1024, (long long)DMODEL * SEQL, 1.0f, 8);
  reduce_out<<<(DMODEL * SEQL / 4) / 256, b256, 0, stream>>>(Pp, bo, out);
}

// Round 9
// 366.569 us; speedup vs baseline: 1.3378x; 1.0072x over previous
//
#include <hip/hip_runtime.h>

#define SEQL 2048
#define DMODEL 1024
#define HDIM 8192  // H*D

typedef unsigned short bf16_t;
typedef __attribute__((ext_vector_type(8))) short bf16x8;
typedef __attribute__((ext_vector_type(4))) float f32x4;

__device__ __forceinline__ bf16_t f2bf(float f) {
  unsigned u = __float_as_uint(f);
  u += 0x7fffu + ((u >> 16) & 1u);  // RNE
  return (bf16_t)(u >> 16);
}
__device__ __forceinline__ float bf2f(bf16_t b) {
  return __uint_as_float(((unsigned)b) << 16);
}

// ---------------- elementwise f32 -> bf16 ----------------
__global__ __launch_bounds__(256) void cvt_f32_bf16(const float* __restrict__ in,
                                                    bf16_t* __restrict__ out, int n) {
  int i = (blockIdx.x * 256 + threadIdx.x) * 4;
  if (i >= n) return;
  float4 f = *reinterpret_cast<const float4*>(in + i);
  ushort4 u;
  u.x = f2bf(f.x); u.y = f2bf(f.y); u.z = f2bf(f.z); u.w = f2bf(f.w);
  *reinterpret_cast<ushort4*>(out + i) = u;
}

// three f32 weight matrices (8192x1024 each) -> one concatenated bf16 buffer
__global__ __launch_bounds__(256) void cvt3_f32_bf16(const float* __restrict__ a,
                                                     const float* __restrict__ b,
                                                     const float* __restrict__ c,
                                                     bf16_t* __restrict__ out) {
  const int SEG = HDIM * DMODEL;  // 8388608
  int i = (blockIdx.x * 256 + threadIdx.x) * 4;
  const float* src;
  int off;
  if (i < SEG) { src = a; off = i; }
  else if (i < 2 * SEG) { src = b; off = i - SEG; }
  else { src = c; off = i - 2 * SEG; }
  float4 f = *reinterpret_cast<const float4*>(src + off);
  ushort4 u;
  u.x = f2bf(f.x); u.y = f2bf(f.y); u.z = f2bf(f.z); u.w = f2bf(f.w);
  *reinterpret_cast<ushort4*>(out + i) = u;
}

// concat bq,bk,bv (8192 each) -> 24576 f32
__global__ __launch_bounds__(256) void bias3(const float* __restrict__ a,
                                             const float* __restrict__ b,
                                             const float* __restrict__ c,
                                             float* __restrict__ out) {
  int i = blockIdx.x * 256 + threadIdx.x;
  float v = (i < HDIM) ? a[i] : (i < 2 * HDIM) ? b[i - HDIM] : c[i - 2 * HDIM];
  out[i] = v;
}

// tokens (DMODEL x SEQL) f32 -> tokensT (SEQL x DMODEL) bf16
__global__ __launch_bounds__(256) void transpose_cvt(const float* __restrict__ in,
                                                     bf16_t* __restrict__ out) {
  __shared__ float tile[32][33];
  int bx = blockIdx.x * 32;  // seq j
  int by = blockIdx.y * 32;  // channel c
  int tx = threadIdx.x, ty = threadIdx.y;
#pragma unroll
  for (int i = ty; i < 32; i += 8)
    tile[i][tx] = in[(size_t)(by + i) * SEQL + bx + tx];
  __syncthreads();
#pragma unroll
  for (int i = ty; i < 32; i += 8)
    out[(size_t)(bx + i) * DMODEL + by + tx] = f2bf(tile[tx][i]);
}

// softmax over the 8 heads (dim 0), in place on bf16 S[8][L*L]
__global__ __launch_bounds__(256) void softmax_heads(bf16_t* __restrict__ S) {
  const size_t HS = (size_t)SEQL * SEQL;
  size_t p = ((size_t)blockIdx.x * 256 + threadIdx.x) * 8;
  float v[8][8];
#pragma unroll
  for (int h = 0; h < 8; ++h) {
    bf16x8 x = *reinterpret_cast<const bf16x8*>(S + h * HS + p);
#pragma unroll
    for (int e = 0; e < 8; ++e) v[h][e] = bf2f((bf16_t)x[e]);
  }
#pragma unroll
  for (int e = 0; e < 8; ++e) {
    float mx = v[0][e];
#pragma unroll
    for (int h = 1; h < 8; ++h) mx = fmaxf(mx, v[h][e]);
    float s = 0.f;
#pragma unroll
    for (int h = 0; h < 8; ++h) { v[h][e] = __expf(v[h][e] - mx); s += v[h][e]; }
    float inv = 1.0f / s;
#pragma unroll
    for (int h = 0; h < 8; ++h) v[h][e] *= inv;
  }
#pragma unroll
  for (int h = 0; h < 8; ++h) {
    bf16x8 x;
#pragma unroll
    for (int e = 0; e < 8; ++e) x[e] = (short)f2bf(v[h][e]);
    *reinterpret_cast<bf16x8*>(S + h * HS + p) = x;
  }
}

// reduce 8 f32 split-K partials P[z][D][L] -> out[D][L] + bias[row]
__global__ __launch_bounds__(256) void reduce_out(const float* __restrict__ P,
                                                  const float* __restrict__ bo,
                                                  float* __restrict__ out) {
  const size_t NEL = (size_t)DMODEL * SEQL;
  size_t i = ((size_t)blockIdx.x * 256 + threadIdx.x) * 4;
  float4 a = *reinterpret_cast<const float4*>(P + i);
#pragma unroll
  for (int z = 1; z < 8; ++z) {
    float4 b = *reinterpret_cast<const float4*>(P + z * NEL + i);
    a.x += b.x; a.y += b.y; a.z += b.z; a.w += b.w;
  }
  float bias = bo[i / SEQL];
  a.x += bias; a.y += bias; a.z += bias; a.w += bias;
  *reinterpret_cast<float4*>(out + i) = a;
}

// ---------------- C = scale * A·B^T (+bias[row]), 256x256 tile ----------------
// R5/R8 core (best measured): 512 thr = 8 waves (2M x 4N), BK=64, double-
// buffered LDS, 4 free-run MFMA groups per K-tile, stages in groups 0-1, one
// __syncthreads per tile. 8-slot XOR swizzle both sides (rule #21).
// Z-FLATTENED 1D GRID: grid.x = nz*gy*gx; after the XCD-chunk swizzle,
// z = swz/gxy, so each XCD's contiguous chunk maps to ONE z (head / K-chunk)
// -> per-XCD L2 working set is one head's panels instead of all 8 (fixes the
// measured 2.3x re-fetch on scores/ctx/out).
// Epilogues (LDS C-staging, coalesced):
//   EPI 0 (bf16): acc -> LDS [256][264] -> b128 -> 16B stores.
//   EPI 1 (f32): two halves [128][264] f32.
//   EPI 2 (fused QKV): rows < 16384 -> EPI0 into C (Qm||Km contiguous);
//     rows >= 16384 -> VSPLIT into C2 = Vs[h][d][m]:
//     g=vrow+i, tok=bcol+dloc; m=g>>2, h2=g&3(=j), r=tok>>10, d=tok&1023.
template <typename OutT, int EPI, bool HAS_BIAS>
__global__ __launch_bounds__(512, 2) void gemm256(
    const bf16_t* __restrict__ A, const bf16_t* __restrict__ B,
    OutT* __restrict__ C, bf16_t* __restrict__ C2, const float* __restrict__ bias,
    int K, int lda, int ldb, int ldc,
    long long sA, long long sB, long long sC, float scale, int gx, int gxy) {
  __shared__ alignas(16) char smem[147456];  // 144 KB arena
  auto* As = reinterpret_cast<bf16_t(*)[2][8192]>(smem);  // [buf][half][128*64]
  auto* Bs = reinterpret_cast<bf16_t(*)[2][8192]>(smem + 65536);
  const int nwg = gridDim.x;
  const int bid = blockIdx.x;
  const int swz = (nwg & 7) ? bid : ((bid & 7) * (nwg >> 3) + (bid >> 3));
  const int zz = swz / gxy;
  const int rem = swz - zz * gxy;
  const int brow = (rem / gx) * 256;
  const int bcol = (rem % gx) * 256;
  A += (long long)zz * sA;
  B += (long long)zz * sB;
  C += (long long)zz * sC;
  const int tid = threadIdx.x;
  const int w = tid >> 6, lane = tid & 63;
  const int fr = lane & 15, fq = lane >> 4;
  const int wr = w >> 2, wc = w & 3;

  int rj[2], cj[2];
#pragma unroll
  for (int j = 0; j < 2; ++j) {
    const int c = (w * 2 + j) * 64 + lane;
    rj[j] = c >> 3;
    cj[j] = ((c & 7) ^ (rj[j] & 7)) << 3;
  }

  auto stageA = [&](int buf, int half, int kk) {
#pragma unroll
    for (int j = 0; j < 2; ++j) {
      const bf16_t* g = A + (size_t)(brow + half * 128 + rj[j]) * lda + kk + cj[j];
      __builtin_amdgcn_global_load_lds(
          (const __attribute__((address_space(1))) void*)g,
          (__attribute__((address_space(3))) void*)(&As[buf][half][(w * 2 + j) * 512]),
          16, 0, 0);
    }
  };
  auto stageB = [&](int buf, int half, int kk) {
#pragma unroll
    for (int j = 0; j < 2; ++j) {
      const bf16_t* g = B + (size_t)(bcol + half * 128 + rj[j]) * ldb + kk + cj[j];
      __builtin_amdgcn_global_load_lds(
          (const __attribute__((address_space(1))) void*)g,
          (__attribute__((address_space(3))) void*)(&Bs[buf][half][(w * 2 + j) * 512]),
          16, 0, 0);
    }
  };

  auto ldA = [&](int buf, int mf, int kk) -> bf16x8 {
    const int rr = mf * 16 + fr;
    return *reinterpret_cast<const bf16x8*>(
        &As[buf][wr][rr * 64 + ((((kk << 2) | fq) ^ (rr & 7)) << 3)]);
  };
  auto ldB = [&](int buf, int nf, int kk) -> bf16x8 {
    const int rr = (wc & 1) * 64 + nf * 16 + fr;
    return *reinterpret_cast<const bf16x8*>(
        &Bs[buf][wc >> 1][rr * 64 + ((((kk << 2) | fq) ^ (rr & 7)) << 3)]);
  };

  f32x4 acc[8][4];
  const f32x4 fzero = {0.f, 0.f, 0.f, 0.f};
#pragma unroll
  for (int m = 0; m < 8; ++m)
#pragma unroll
    for (int n = 0; n < 4; ++n) acc[m][n] = fzero;

  const int NT = K >> 6;  // K % 64 == 0, NT >= 2 at all call sites
  stageA(0, 0, 0); stageA(0, 1, 0); stageB(0, 0, 0); stageB(0, 1, 0);
  __syncthreads();

  for (int t = 0; t < NT; ++t) {
    const int p = t & 1, q = p ^ 1;
    const int kn = (t + 1) << 6;
    const bool pre = (t + 1 < NT);
    bf16x8 af[4][2], bg[4][2];

    // ---- group 0: rows 0-63 x cols 0-31 ----
    if (pre) { stageA(q, 0, kn); stageA(q, 1, kn); }
#pragma unroll
    for (int mf = 0; mf < 4; ++mf)
#pragma unroll
      for (int kk = 0; kk < 2; ++kk) af[mf][kk] = ldA(p, mf, kk);
#pragma unroll
    for (int nf = 0; nf < 2; ++nf)
#pragma unroll
      for (int kk = 0; kk < 2; ++kk) bg[nf][kk] = ldB(p, nf, kk);
    __builtin_amdgcn_s_setprio(1);
#pragma unroll
    for (int mf = 0; mf < 4; ++mf)
#pragma unroll
      for (int nf = 0; nf < 2; ++nf)
#pragma unroll
        for (int kk = 0; kk < 2; ++kk)
          acc[mf][nf] = __builtin_amdgcn_mfma_f32_16x16x32_bf16(
              af[mf][kk], bg[nf][kk], acc[mf][nf], 0, 0, 0);
    __builtin_amdgcn_s_setprio(0);

    // ---- group 1: rows 0-63 x cols 32-63 ----
    if (pre) { stageB(q, 0, kn); stageB(q, 1, kn); }
#pragma unroll
    for (int nf = 2; nf < 4; ++nf)
#pragma unroll
      for (int kk = 0; kk < 2; ++kk) bg[nf][kk] = ldB(p, nf, kk);
    __builtin_amdgcn_s_setprio(1);
#pragma unroll
    for (int mf = 0; mf < 4; ++mf)
#pragma unroll
      for (int nf = 2; nf < 4; ++nf)
#pragma unroll
        for (int kk = 0; kk < 2; ++kk)
          acc[mf][nf] = __builtin_amdgcn_mfma_f32_16x16x32_bf16(
              af[mf][kk], bg[nf][kk], acc[mf][nf], 0, 0, 0);
    __builtin_amdgcn_s_setprio(0);

    // ---- group 2: rows 64-127 x cols 32-63 ----
#pragma unroll
    for (int mf = 0; mf < 4; ++mf)
#pragma unroll
      for (int kk = 0; kk < 2; ++kk) af[mf][kk] = ldA(p, mf + 4, kk);
    __builtin_amdgcn_s_setprio(1);
#pragma unroll
    for (int mf = 0; mf < 4; ++mf)
#pragma unroll
      for (int nf = 2; nf < 4; ++nf)
#pragma unroll
        for (int kk = 0; kk < 2; ++kk)
          acc[mf + 4][nf] = __builtin_amdgcn_mfma_f32_16x16x32_bf16(
              af[mf][kk], bg[nf][kk], acc[mf + 4][nf], 0, 0, 0);
    __builtin_amdgcn_s_setprio(0);

    // ---- group 3: rows 64-127 x cols 0-31 ----
#pragma unroll
    for (int nf = 0; nf < 2; ++nf)
#pragma unroll
      for (int kk = 0; kk < 2; ++kk) bg[nf][kk] = ldB(p, nf, kk);
    __builtin_amdgcn_s_setprio(1);
#pragma unroll
    for (int mf = 0; mf < 4; ++mf)
#pragma unroll
      for (int nf = 0; nf < 2; ++nf)
#pragma unroll
        for (int kk = 0; kk < 2; ++kk)
          acc[mf + 4][nf] = __builtin_amdgcn_mfma_f32_16x16x32_bf16(
              af[mf][kk], bg[nf][kk], acc[mf + 4][nf], 0, 0, 0);
    __builtin_amdgcn_s_setprio(0);

    if (pre) __syncthreads();
  }

  // ======== epilogues (LDS C-staging, coalesced stores) ========
  __syncthreads();  // all waves' LDS reads retired -> arena reusable

  const bool vseg = (EPI == 2) && (brow >= 2 * HDIM);
  if ((EPI == 0) || ((EPI == 2) && !vseg)) {  // bf16 C, [256][264] staging
    bf16_t* Ct = (bf16_t*)smem;
#pragma unroll
    for (int mf = 0; mf < 8; ++mf)
#pragma unroll
      for (int j = 0; j < 4; ++j) {
        const int orow = wr * 128 + mf * 16 + fq * 4 + j;
        float bvv = HAS_BIAS ? bias[brow + orow] : 0.f;
#pragma unroll
        for (int nf = 0; nf < 4; ++nf)
          Ct[orow * 264 + wc * 64 + nf * 16 + fr] = f2bf(acc[mf][nf][j] * scale + bvv);
      }
    __syncthreads();
    bf16_t* Cb = (bf16_t*)C;
#pragma unroll
    for (int i = 0; i < 16; ++i) {
      const int c = tid + i * 512;        // 16B chunk id, 8192 total
      const int row = c >> 5, ch = c & 31;
      *reinterpret_cast<bf16x8*>(&Cb[(size_t)(brow + row) * ldc + bcol + ch * 8]) =
          *reinterpret_cast<const bf16x8*>(smem + row * 528 + ch * 16);
    }
  } else if constexpr (EPI == 1) {  // f32 C, two halves [128][264] f32
    float* Cf = (float*)smem;
#pragma unroll
    for (int h = 0; h < 2; ++h) {
      if (wr == h) {
#pragma unroll
        for (int mf = 0; mf < 8; ++mf)
#pragma unroll
          for (int j = 0; j < 4; ++j) {
            const int orow = mf * 16 + fq * 4 + j;  // 0..127
            float bvv = HAS_BIAS ? bias[brow + h * 128 + orow] : 0.f;
#pragma unroll
            for (int nf = 0; nf < 4; ++nf)
              Cf[orow * 264 + wc * 64 + nf * 16 + fr] = acc[mf][nf][j] * scale + bvv;
          }
      }
      __syncthreads();
#pragma unroll
      for (int i = 0; i < 16; ++i) {
        const int c = tid + i * 512;      // 16B chunk id, 8192 total
        const int row = c >> 6, ch = c & 63;
        *reinterpret_cast<float4*>(&C[(size_t)(brow + h * 128 + row) * ldc + bcol + ch * 4]) =
            *reinterpret_cast<const float4*>(smem + row * 1056 + ch * 16);
      }
      __syncthreads();
    }
  } else if constexpr (EPI == 2) {  // V rows -> Vs[8][1024][2048] via C2
    const int vrow = brow - 2 * HDIM;
    bf16_t* Vt = (bf16_t*)smem;  // [4][256][72]: (h2, dloc, mloc)
#pragma unroll
    for (int mf = 0; mf < 8; ++mf)
#pragma unroll
      for (int j = 0; j < 4; ++j) {
        const int i = wr * 128 + mf * 16 + fq * 4 + j;  // local row; h2 = i&3 = j
        const int mloc = i >> 2;
        float bvv = HAS_BIAS ? bias[brow + i] : 0.f;
#pragma unroll
        for (int nf = 0; nf < 4; ++nf) {
          const int dloc = wc * 64 + nf * 16 + fr;
          Vt[(j * 256 + dloc) * 72 + mloc] = f2bf(acc[mf][nf][j] * scale + bvv);
        }
      }
    __syncthreads();
    const int r_ = bcol >> 10, d0 = bcol & 1023, m0 = vrow >> 2;
#pragma unroll
    for (int sIt = 0; sIt < 2; ++sIt) {
      const int s = tid + sIt * 512;      // seg id: 4 h2 x 256 dloc
      const int h2 = s >> 8, dloc = s & 255;
      const bf16_t* src = Vt + (h2 * 256 + dloc) * 72;
      bf16_t* dst = C2 + ((size_t)(2 * h2 + r_) * DMODEL + d0 + dloc) * SEQL + m0;
#pragma unroll
      for (int qq = 0; qq < 8; ++qq)
        *reinterpret_cast<bf16x8*>(dst + qq * 8) =
            *reinterpret_cast<const bf16x8*>(src + qq * 8);
    }
  }
}

extern "C" void kernel_launch(void* const* d_in, const int* in_sizes, int n_in,
                              void* d_out, int out_size, void* d_ws, size_t ws_size,
                              hipStream_t stream) {
  const float* tokens = (const float*)d_in[0];
  const float* Wq = (const float*)d_in[1];
  const float* bq = (const float*)d_in[2];
  const float* Wk = (const float*)d_in[3];
  const float* bk = (const float*)d_in[4];
  const float* Wv = (const float*)d_in[5];
  const float* bv = (const float*)d_in[6];
  const float* Wo = (const float*)d_in[7];
  const float* bo = (const float*)d_in[8];
  float* out = (float*)d_out;
  char* ws = (char*)d_ws;
  const size_t MB = 1024ull * 1024ull;
  // workspace layout (peak 160 MB):
  bf16_t* Vs = (bf16_t*)(ws + 0);          // Vsplit 32 MB [0,32)
  bf16_t* QmKm = (bf16_t*)(ws + 32 * MB);  // Qm||Km 64 MB [32,96)
  bf16_t* Qm = QmKm;                       // rows [0,8192)
  bf16_t* Km = QmKm + (size_t)HDIM * SEQL; // rows [8192,16384)
  bf16_t* Sb = (bf16_t*)(ws + 96 * MB);    // scores/attn 64 MB [96,160)
  bf16_t* tT = (bf16_t*)(ws + 96 * MB);    // tokensT 4 MB [96,100) (dead before Sb)
  bf16_t* Wqkv = (bf16_t*)(ws + 100 * MB); // 48 MB [100,148) (dead before Sb)
  float* bqkv = (float*)(ws + 148 * MB);   // 96 KB (dead before Sb)
  bf16_t* cT = (bf16_t*)(ws + 32 * MB);    // ctxT 32 MB (reuse Qm after scores)
  bf16_t* Wob = (bf16_t*)(ws + 64 * MB);   // Wo bf16 16 MB (reuse Km after scores)
  float* Pp = (float*)(ws + 96 * MB);      // split-K partials 64 MB (reuse Sb)

  dim3 b256(256);
  dim3 b512(512);
  const int nW = HDIM * DMODEL;  // 8388608

  // prep: tokensT, concatenated bf16 weights, concatenated bias
  transpose_cvt<<<dim3(SEQL / 32, DMODEL / 32), dim3(32, 8), 0, stream>>>(tokens, tT);
  cvt3_f32_bf16<<<3 * nW / 1024, b256, 0, stream>>>(Wq, Wk, Wv, Wqkv);
  bias3<<<3 * HDIM / 256, b256, 0, stream>>>(bq, bk, bv, bqkv);

  // fused QKV projection: M=24576, N=2048, K=1024; Q/K rows -> QmKm,
  // V rows -> Vs (VSPLIT). grid 96x8 = 768 blocks, 1D, XCD-chunked.
  gemm256<bf16_t, 2, true><<<dim3(768, 1, 1), b512, 0, stream>>>(
      Wqkv, tT, QmKm, Vs, bqkv, DMODEL, DMODEL, DMODEL, SEQL,
      0, 0, 0, 1.0f, 8, 768);

  // scores[h][l,m] = (1/32) dot(Qm[l*8192+h*1024+:], Km[m*8192+h*1024+:])
  // z folded head-major: grid 8z*8y*8x = 512; each XCD owns one head.
  gemm256<bf16_t, 0, false><<<dim3(512, 1, 1), b512, 0, stream>>>(
      Qm, Km, Sb, nullptr, nullptr, DMODEL, HDIM, HDIM, SEQL,
      1024, 1024, (long long)SEQL * SEQL, 0.03125f, 8, 64);

  // softmax over heads (dim 0), in place
  softmax_heads<<<(SEQL * SEQL / 8) / 256, b256, 0, stream>>>(Sb);

  // ctxT[l, h*1024+d] = sum_m attn[h][l,m] * Vs[h][d,m]; grid 8z*8y*4x = 256.
  gemm256<bf16_t, 0, false><<<dim3(256, 1, 1), b512, 0, stream>>>(
      Sb, Vs, cT, nullptr, nullptr, SEQL, SEQL, SEQL, HDIM,
      (long long)SEQL * SEQL, (long long)DMODEL * SEQL, 1024, 1.0f, 4, 32);

  // out = Wo · ctxT^T + bo (f32), split-K=8 over K=8192; grid 8z*4y*8x = 256.
  cvt_f32_bf16<<<nW / 1024, b256, 0, stream>>>(Wo, Wob, nW);
  gemm256<float, 1, false><<<dim3(256, 1, 1), b512, 0, stream>>>(
      Wob, cT, Pp, nullptr, nullptr, 1024, HDIM, HDIM, SEQL,
      1024, 1024, (long long)DMODEL * SEQL, 1.0f, 8, 32);
  reduce_out<<<(DMODEL * SEQL / 4) / 256, b256, 0, stream>>>(Pp, bo, out);
}